// Round 2
// baseline (727.776 us; speedup 1.0000x reference)
//
#include <hip/hip_runtime.h>

typedef _Float16 half8 __attribute__((ext_vector_type(8)));
typedef float floatx4 __attribute__((ext_vector_type(4)));

#define DDIM 64
#define LN_EPS 1e-5f
#define SHIFT 20.0f

#define RB 128    // query rows per block
#define CK 64     // C rows (score cols) per chunk

__device__ inline float wave_sum(float v) {
#pragma unroll
  for (int m = 1; m < 64; m <<= 1) v += __shfl_xor(v, m, 64);
  return v;
}

__device__ inline void gld16(const void* g, void* l) {
  __builtin_amdgcn_global_load_lds(
      (const __attribute__((address_space(1))) void*)g,
      (__attribute__((address_space(3))) void*)l, 16, 0, 0);
}

// LayerNorm both tables, emit f16 hi/lo split planes. One wave per row.
__global__ __launch_bounds__(256) void ln_kernel(
    const float* __restrict__ Eo, const float* __restrict__ Ed,
    const float* __restrict__ go, const float* __restrict__ bo,
    const float* __restrict__ gd, const float* __restrict__ bd,
    _Float16* __restrict__ Co_hi, _Float16* __restrict__ Co_lo,
    _Float16* __restrict__ Cd_hi, _Float16* __restrict__ Cd_lo, int N) {
  int row = blockIdx.x * 4 + (threadIdx.x >> 6);
  if (row >= N) return;
  int lane = threadIdx.x & 63;
  size_t idx = (size_t)row * DDIM + lane;
  {
    float x = Eo[idx];
    float m = wave_sum(x) * (1.0f / DDIM);
    float d = x - m;
    float var = wave_sum(d * d) * (1.0f / DDIM);
    float y = d * rsqrtf(var + LN_EPS) * go[lane] + bo[lane];
    _Float16 hi = (_Float16)y;
    Co_hi[idx] = hi;
    Co_lo[idx] = (_Float16)(y - (float)hi);
  }
  {
    float x = Ed[idx];
    float m = wave_sum(x) * (1.0f / DDIM);
    float d = x - m;
    float var = wave_sum(d * d) * (1.0f / DDIM);
    float y = d * rsqrtf(var + LN_EPS) * gd[lane] + bd[lane];
    _Float16 hi = (_Float16)y;
    Cd_hi[idx] = hi;
    Cd_lo[idx] = (_Float16)(y - (float)hi);
  }
}

// SINGLE-PASS: write p = exp(score - SHIFT) unnormalized to out, accumulate
// per-row sums via atomics. Scores via split-f16 MFMA:
// s = qh*ch + qh*cl + ql*ch (ql*cl dropped, ~2^-22).
// LDS budget = 32 KB total: Q planes staged into the SAME buffer that later
// holds the C double-buffer (Q only feeds persistent A-register fragments).
// C tiles double-buffered via global_load_lds (linear LDS dest, XOR-swizzled
// global source); counted vmcnt (never 0 mid-loop; accounts for the 32
// output stores that share the counter) keeps prefetch in flight.
__global__ __launch_bounds__(256, 2) void score_kernel(
    const _Float16* __restrict__ Co_hi, const _Float16* __restrict__ Co_lo,
    const _Float16* __restrict__ Cd_hi, const _Float16* __restrict__ Cd_lo,
    const int* __restrict__ ids, float* __restrict__ sums,
    float* __restrict__ out, int N, int B, int nc_total) {
  // [buf][hi/lo][64 rows * 64 halves] = 32768 B. Rows linear 128 B,
  // 16B-blocks XOR-swizzled by (row&7).
  __shared__ __attribute__((aligned(16))) _Float16 Cb[2][2][CK * DDIM];

  const int t = threadIdx.x;
  const int mat = blockIdx.z;
  const int mbase = blockIdx.y * RB;
  const _Float16* Qsrc_h = (mat == 0) ? Co_hi : Cd_hi;
  const _Float16* Qsrc_l = (mat == 0) ? Co_lo : Cd_lo;
  const _Float16* Csrc_h = (mat == 0) ? Cd_hi : Co_hi;
  const _Float16* Csrc_l = (mat == 0) ? Cd_lo : Co_lo;

  const int lane = t & 63;
  const int wv = t >> 6;
  const int l15 = lane & 15;
  const int quad = lane >> 4;

  // ---- Stage Q (gathered rows) into the Cb area: [128 rows][64 halves]
  // per plane, XOR-swizzled 16B blocks. Read A frags, then reuse the LDS.
  _Float16* Qh_lds = &Cb[0][0][0];  // 16384 B
  _Float16* Ql_lds = &Cb[1][0][0];  // 16384 B
#pragma unroll
  for (int rnd = 0; rnd < 4; ++rnd) {
    int f = (rnd * 256 + t) * 16;   // byte offset in plane image [128][128B]
    int r = f >> 7;
    int off = f & 127;
    int swoff = off ^ ((r & 7) << 4);
    int id = ids[mbase + r];
    *(uint4*)((char*)Qh_lds + r * 128 + swoff) =
        *(const uint4*)((const char*)Qsrc_h + (size_t)id * 128 + off);
    *(uint4*)((char*)Ql_lds + r * 128 + swoff) =
        *(const uint4*)((const char*)Qsrc_l + (size_t)id * 128 + off);
  }
  __syncthreads();

  // A fragments (persistent in registers): wave handles m-tiles {2wv, 2wv+1}
  half8 Ah[2][2], Al[2][2];
#pragma unroll
  for (int mt = 0; mt < 2; ++mt) {
    int r = wv * 32 + mt * 16 + l15;
    int sw = (r & 7) << 4;
    const char* qh = (const char*)Qh_lds + r * 128;
    const char* ql = (const char*)Ql_lds + r * 128;
    Ah[mt][0] = *(const half8*)(qh + ((quad * 16) ^ sw));
    Ah[mt][1] = *(const half8*)(qh + ((64 + quad * 16) ^ sw));
    Al[mt][0] = *(const half8*)(ql + ((quad * 16) ^ sw));
    Al[mt][1] = *(const half8*)(ql + ((64 + quad * 16) ^ sw));
  }
  __syncthreads();  // all waves have A frags; Cb is now free for C tiles

  // Async stage of one chunk (both planes) into buf. Per wave: 4 gld16.
  // LDS slot s (16 B, linear) holds row r = s>>3, global block (s&7)^(r&7).
  auto stage = [&](int chunk, int buf) {
    int nbase = chunk * CK;
    #pragma unroll
    for (int j = 0; j < 2; ++j) {
      int slot = wv * 128 + j * 64 + lane;
      int r = slot >> 3;
      int gr = nbase + r;
      if (gr > N - 1) gr = N - 1;  // clamp; masked at use
      int gb = (slot & 7) ^ (r & 7);
      size_t goff = (size_t)gr * 128 + (size_t)(gb * 16);
      _Float16* dh = &Cb[buf][0][(wv * 128 + j * 64) * 8];  // wave-uniform base
      _Float16* dl = &Cb[buf][1][(wv * 128 + j * 64) * 8];
      gld16((const char*)Csrc_h + goff, dh);
      gld16((const char*)Csrc_l + goff, dl);
    }
  };

  float sumacc[2][4];
#pragma unroll
  for (int mt = 0; mt < 2; ++mt)
#pragma unroll
    for (int r = 0; r < 4; ++r) sumacc[mt][r] = 0.0f;

  const int bx = blockIdx.x;
  const int gxd = gridDim.x;
  // strided chunk assignment: chunks bx, bx+gxd, bx+2*gxd, ...
  int nck = (bx < nc_total) ? ((nc_total - 1 - bx) / gxd + 1) : 0;
  float* orow = out + (size_t)mat * B * N + (size_t)mbase * N;

  if (nck > 0) stage(bx, 0);

  for (int k = 0; k < nck; ++k) {
    int cur = k & 1;
    bool pf = (k + 1 < nck);
    if (pf) stage(bx + (k + 1) * gxd, cur ^ 1);
    // vmcnt budget = ops issued after the 4 loads of buf[cur]:
    //   k=0 : 4 prefetch loads (or 0 if none)
    //   k>=1: 32 stores of chunk k-1 + 4 prefetch loads (or 32 w/o prefetch)
    if (k == 0) {
      if (pf) asm volatile("s_waitcnt vmcnt(4)" ::: "memory");
      else    asm volatile("s_waitcnt vmcnt(0)" ::: "memory");
    } else {
      if (pf) asm volatile("s_waitcnt vmcnt(36)" ::: "memory");
      else    asm volatile("s_waitcnt vmcnt(32)" ::: "memory");
    }
    __builtin_amdgcn_sched_barrier(0);
    __builtin_amdgcn_s_barrier();
    __builtin_amdgcn_sched_barrier(0);

    int nbase = (bx + k * gxd) * CK;
    const _Float16* ChL = &Cb[cur][0][0];
    const _Float16* ClL = &Cb[cur][1][0];
#pragma unroll
    for (int nt = 0; nt < 4; ++nt) {
      int cr = nt * 16 + l15;
      int sw = (cr & 7) << 4;
      const char* bh = (const char*)ChL + cr * 128;
      const char* bl = (const char*)ClL + cr * 128;
      half8 Bh0 = *(const half8*)(bh + ((quad * 16) ^ sw));
      half8 Bh1 = *(const half8*)(bh + ((64 + quad * 16) ^ sw));
      half8 Bl0 = *(const half8*)(bl + ((quad * 16) ^ sw));
      half8 Bl1 = *(const half8*)(bl + ((64 + quad * 16) ^ sw));
      int col = nbase + nt * 16 + l15;
      bool valid = col < N;
#pragma unroll
      for (int mt = 0; mt < 2; ++mt) {
        floatx4 acc = {0.0f, 0.0f, 0.0f, 0.0f};
        acc = __builtin_amdgcn_mfma_f32_16x16x32_f16(Ah[mt][0], Bh0, acc, 0, 0, 0);
        acc = __builtin_amdgcn_mfma_f32_16x16x32_f16(Ah[mt][1], Bh1, acc, 0, 0, 0);
        acc = __builtin_amdgcn_mfma_f32_16x16x32_f16(Ah[mt][0], Bl0, acc, 0, 0, 0);
        acc = __builtin_amdgcn_mfma_f32_16x16x32_f16(Ah[mt][1], Bl1, acc, 0, 0, 0);
        acc = __builtin_amdgcn_mfma_f32_16x16x32_f16(Al[mt][0], Bh0, acc, 0, 0, 0);
        acc = __builtin_amdgcn_mfma_f32_16x16x32_f16(Al[mt][1], Bh1, acc, 0, 0, 0);
#pragma unroll
        for (int r = 0; r < 4; ++r) {
          float p = __expf(acc[r] - SHIFT);
          p = valid ? p : 0.0f;
          sumacc[mt][r] += p;
          if (valid) {
            int rl = wv * 32 + mt * 16 + quad * 4 + r;
            orow[(size_t)rl * N + col] = p;
          }
        }
      }
    }
    __builtin_amdgcn_sched_barrier(0);
    __builtin_amdgcn_s_barrier();  // all waves done reading buf[cur] before overwrite
  }

  // per-row partial sums -> atomics (reduce across the 16 lanes of each row group)
#pragma unroll
  for (int mt = 0; mt < 2; ++mt)
#pragma unroll
    for (int r = 0; r < 4; ++r) {
      float v = sumacc[mt][r];
      v += __shfl_xor(v, 1, 64);
      v += __shfl_xor(v, 2, 64);
      v += __shfl_xor(v, 4, 64);
      v += __shfl_xor(v, 8, 64);
      if (l15 == 0) {
        int rl = wv * 32 + mt * 16 + quad * 4 + r;
        atomicAdd(&sums[(size_t)mat * B + mbase + rl], v);
      }
    }
}

// out[row, :] *= 1/sums[row] — pure BW-bound stream (819 MB), float4.
__global__ __launch_bounds__(256) void rescale_kernel(
    float* __restrict__ out, const float* __restrict__ sums, int N) {
  int row = blockIdx.y;
  float inv = 1.0f / sums[row];
  float4* po = (float4*)(out + (size_t)row * N);
  int nf4 = N >> 2;
  for (int i = blockIdx.x * blockDim.x + threadIdx.x; i < nf4;
       i += gridDim.x * blockDim.x) {
    float4 v = po[i];
    v.x *= inv; v.y *= inv; v.z *= inv; v.w *= inv;
    po[i] = v;
  }
  if ((N & 3) && blockIdx.x == 0 && threadIdx.x < (N & 3)) {
    int idx = (nf4 << 2) + threadIdx.x;
    out[(size_t)row * N + idx] *= inv;
  }
}

extern "C" void kernel_launch(void* const* d_in, const int* in_sizes, int n_in,
                              void* d_out, int out_size, void* d_ws, size_t ws_size,
                              hipStream_t stream) {
  const int* ids = (const int*)d_in[0];
  const float* Eo = (const float*)d_in[1];
  const float* Ed = (const float*)d_in[2];
  const float* go = (const float*)d_in[3];
  const float* bo = (const float*)d_in[4];
  const float* gd = (const float*)d_in[5];
  const float* bd = (const float*)d_in[6];
  const int B = in_sizes[0];          // 512
  const int N = in_sizes[1] / DDIM;   // 100000
  float* out = (float*)d_out;

  char* ws = (char*)d_ws;
  size_t plane = (size_t)N * DDIM * sizeof(_Float16);  // 12.8 MB
  _Float16* Co_hi = (_Float16*)(ws + 0 * plane);
  _Float16* Co_lo = (_Float16*)(ws + 1 * plane);
  _Float16* Cd_hi = (_Float16*)(ws + 2 * plane);
  _Float16* Cd_lo = (_Float16*)(ws + 3 * plane);
  float* sums = (float*)(ws + 4 * plane);  // 2*B floats

  hipMemsetAsync(sums, 0, (size_t)2 * B * sizeof(float), stream);

  ln_kernel<<<(N + 3) / 4, 256, 0, stream>>>(Eo, Ed, go, bo, gd, bd,
                                             Co_hi, Co_lo, Cd_hi, Cd_lo, N);

  int nc_total = (N + CK - 1) / CK;  // 1563
  // 192 x-blocks * 4 * 2 = 1536 blocks = exactly 3 rounds at 2 blocks/CU;
  // strided chunk assignment balances 8-vs-9 chunks per block.
  dim3 sgrid(192, B / RB, 2);
  score_kernel<<<sgrid, 256, 0, stream>>>(Co_hi, Co_lo, Cd_hi, Cd_lo, ids,
                                          sums, out, N, B, nc_total);

  dim3 rgrid(8, 2 * B);  // 8192 blocks, ~12 float4 iters each
  rescale_kernel<<<rgrid, 256, 0, stream>>>(out, sums, N);
}

// Round 4
// 584.218 us; speedup vs baseline: 1.2457x; 1.2457x over previous
//
#include <hip/hip_runtime.h>

typedef _Float16 half8 __attribute__((ext_vector_type(8)));
typedef float floatx4 __attribute__((ext_vector_type(4)));

#define DDIM 64
#define LN_EPS 1e-5f
#define SHIFT 20.0f

#define RB 128        // query rows per block
#define CK 64         // C rows (score cols) per chunk
#define STR 72        // LDS row stride in f16 elems (144 B: 2-way bank alias = free)
#define ROWB (STR * 2)   // 144 bytes per LDS row
#define PLB (CK * ROWB)  // 9216 bytes per plane buffer

__device__ inline float wave_sum(float v) {
#pragma unroll
  for (int m = 1; m < 64; m <<= 1) v += __shfl_xor(v, m, 64);
  return v;
}

// LayerNorm both tables, emit f16 hi/lo split planes. One wave per row.
__global__ __launch_bounds__(256) void ln_kernel(
    const float* __restrict__ Eo, const float* __restrict__ Ed,
    const float* __restrict__ go, const float* __restrict__ bo,
    const float* __restrict__ gd, const float* __restrict__ bd,
    _Float16* __restrict__ Co_hi, _Float16* __restrict__ Co_lo,
    _Float16* __restrict__ Cd_hi, _Float16* __restrict__ Cd_lo, int N) {
  int row = blockIdx.x * 4 + (threadIdx.x >> 6);
  if (row >= N) return;
  int lane = threadIdx.x & 63;
  size_t idx = (size_t)row * DDIM + lane;
  {
    float x = Eo[idx];
    float m = wave_sum(x) * (1.0f / DDIM);
    float d = x - m;
    float var = wave_sum(d * d) * (1.0f / DDIM);
    float y = d * rsqrtf(var + LN_EPS) * go[lane] + bo[lane];
    _Float16 hi = (_Float16)y;
    Co_hi[idx] = hi;
    Co_lo[idx] = (_Float16)(y - (float)hi);
  }
  {
    float x = Ed[idx];
    float m = wave_sum(x) * (1.0f / DDIM);
    float d = x - m;
    float var = wave_sum(d * d) * (1.0f / DDIM);
    float y = d * rsqrtf(var + LN_EPS) * gd[lane] + bd[lane];
    _Float16 hi = (_Float16)y;
    Cd_hi[idx] = hi;
    Cd_lo[idx] = (_Float16)(y - (float)hi);
  }
}

// Two-pass softmax. PASS 0: accumulate sum of exp(score - SHIFT) per row
// (atomics). PASS 1: write exp(score - SHIFT) * inv_sum (nontemporal).
// Scores via split-f16 MFMA: s = qh*ch + qh*cl + ql*ch (ql*cl dropped).
// LDS = 18.9 KB (Q staged through the C buffer in two rounds at startup,
// A-fragments persist in registers) -> 3 blocks/CU at launch_bounds(256,3):
// 12 waves/CU; cross-block TLP hides the per-chunk barrier+load latency.
template <int PASS>
__global__ __launch_bounds__(256, 3) void score_kernel(
    const _Float16* __restrict__ Co_hi, const _Float16* __restrict__ Co_lo,
    const _Float16* __restrict__ Cd_hi, const _Float16* __restrict__ Cd_lo,
    const int* __restrict__ ids, float* __restrict__ sums,
    float* __restrict__ out, int N, int B, int nc_total) {
  // [2 planes][64 rows][144 B] = 18432 B; also reused for Q staging
  // (one plane image = 128 rows x 144 B = 18432 B, staged hi then lo).
  __shared__ __attribute__((aligned(16))) char Sbuf[2 * PLB];
  __shared__ float inv_lds[RB];

  const int t = threadIdx.x;
  const int mat = blockIdx.z;
  const int mbase = blockIdx.y * RB;
  const _Float16* Qsrc_h = (mat == 0) ? Co_hi : Cd_hi;
  const _Float16* Qsrc_l = (mat == 0) ? Co_lo : Cd_lo;
  const _Float16* Csrc_h = (mat == 0) ? Cd_hi : Co_hi;
  const _Float16* Csrc_l = (mat == 0) ? Cd_lo : Co_lo;

  const int lane = t & 63;
  const int wv = t >> 6;
  const int l15 = lane & 15;
  const int quad = lane >> 4;

  if (PASS == 1 && t < RB)
    inv_lds[t] = 1.0f / sums[(size_t)mat * B + mbase + t];

  // ---- Stage Q-hi into Sbuf as [128 rows][144 B], read A-hi frags.
#pragma unroll
  for (int j = 0; j < 4; ++j) {
    int f = (j * 256 + t) * 16;  // byte offset in [128][128B] plane image
    int r = f >> 7;
    int off = f & 127;
    int id = ids[mbase + r];
    *(uint4*)(Sbuf + r * ROWB + off) =
        *(const uint4*)((const char*)Qsrc_h + (size_t)id * 128 + off);
  }
  __syncthreads();
  half8 Ah[2][2], Al[2][2];
#pragma unroll
  for (int mt = 0; mt < 2; ++mt) {
    int r = wv * 32 + mt * 16 + l15;
    const char* q = Sbuf + r * ROWB + quad * 16;
    Ah[mt][0] = *(const half8*)q;
    Ah[mt][1] = *(const half8*)(q + 64);
  }
  float invr[2][4];
  if (PASS == 1) {
#pragma unroll
    for (int mt = 0; mt < 2; ++mt)
#pragma unroll
      for (int r2 = 0; r2 < 4; ++r2)
        invr[mt][r2] = inv_lds[wv * 32 + mt * 16 + quad * 4 + r2];
  }
  __syncthreads();
  // ---- Stage Q-lo (same layout), read A-lo frags.
#pragma unroll
  for (int j = 0; j < 4; ++j) {
    int f = (j * 256 + t) * 16;
    int r = f >> 7;
    int off = f & 127;
    int id = ids[mbase + r];
    *(uint4*)(Sbuf + r * ROWB + off) =
        *(const uint4*)((const char*)Qsrc_l + (size_t)id * 128 + off);
  }
  __syncthreads();
#pragma unroll
  for (int mt = 0; mt < 2; ++mt) {
    int r = wv * 32 + mt * 16 + l15;
    const char* q = Sbuf + r * ROWB + quad * 16;
    Al[mt][0] = *(const half8*)q;
    Al[mt][1] = *(const half8*)(q + 64);
  }
  __syncthreads();  // Q reads done; Sbuf free for C chunks

  float sumacc[2][4];
#pragma unroll
  for (int mt = 0; mt < 2; ++mt)
#pragma unroll
    for (int r2 = 0; r2 < 4; ++r2) sumacc[mt][r2] = 0.0f;

  const int bx = blockIdx.x;
  const int gxd = gridDim.x;
  // strided chunk assignment: chunks bx, bx+gxd, bx+2*gxd, ...
  int nck = (bx < nc_total) ? ((nc_total - 1 - bx) / gxd + 1) : 0;
  float* orow = out + (size_t)mat * B * N + (size_t)mbase * N;

  for (int k = 0; k < nck; ++k) {
    int nbase = (bx + k * gxd) * CK;
    // stage C chunk (both planes): 64 rows x 128 B each, [r][144B] layout
#pragma unroll
    for (int p = 0; p < 2; ++p) {
      const char* src = (p == 0) ? (const char*)Csrc_h : (const char*)Csrc_l;
#pragma unroll
      for (int j = 0; j < 2; ++j) {
        int f = (j * 256 + t) * 16;
        int r = f >> 7;
        int off = f & 127;
        int gr = nbase + r;
        if (gr > N - 1) gr = N - 1;  // clamp; masked at use
        *(uint4*)(Sbuf + p * PLB + r * ROWB + off) =
            *(const uint4*)(src + (size_t)gr * 128 + off);
      }
    }
    __syncthreads();

#pragma unroll
    for (int nt = 0; nt < 4; ++nt) {
      int cr = nt * 16 + l15;
      const char* bh = Sbuf + cr * ROWB + quad * 16;
      const char* bl = bh + PLB;
      half8 Bh0 = *(const half8*)bh;
      half8 Bh1 = *(const half8*)(bh + 64);
      half8 Bl0 = *(const half8*)bl;
      half8 Bl1 = *(const half8*)(bl + 64);
      int col = nbase + nt * 16 + l15;
      bool valid = col < N;
#pragma unroll
      for (int mt = 0; mt < 2; ++mt) {
        floatx4 acc = {0.0f, 0.0f, 0.0f, 0.0f};
        acc = __builtin_amdgcn_mfma_f32_16x16x32_f16(Ah[mt][0], Bh0, acc, 0, 0, 0);
        acc = __builtin_amdgcn_mfma_f32_16x16x32_f16(Ah[mt][1], Bh1, acc, 0, 0, 0);
        acc = __builtin_amdgcn_mfma_f32_16x16x32_f16(Ah[mt][0], Bl0, acc, 0, 0, 0);
        acc = __builtin_amdgcn_mfma_f32_16x16x32_f16(Ah[mt][1], Bl1, acc, 0, 0, 0);
        acc = __builtin_amdgcn_mfma_f32_16x16x32_f16(Al[mt][0], Bh0, acc, 0, 0, 0);
        acc = __builtin_amdgcn_mfma_f32_16x16x32_f16(Al[mt][1], Bh1, acc, 0, 0, 0);
#pragma unroll
        for (int r2 = 0; r2 < 4; ++r2) {
          float p = __expf(acc[r2] - SHIFT);
          if (PASS == 0) {
            sumacc[mt][r2] += valid ? p : 0.0f;
          } else if (valid) {
            int rl = wv * 32 + mt * 16 + quad * 4 + r2;
            __builtin_nontemporal_store(p * invr[mt][r2],
                                        &orow[(size_t)rl * N + col]);
          }
        }
      }
    }
    __syncthreads();  // all waves done reading Sbuf before next stage
  }

  if (PASS == 0) {
    // per-row partial sums -> atomics (reduce across 16 lanes of row group)
#pragma unroll
    for (int mt = 0; mt < 2; ++mt)
#pragma unroll
      for (int r2 = 0; r2 < 4; ++r2) {
        float v = sumacc[mt][r2];
        v += __shfl_xor(v, 1, 64);
        v += __shfl_xor(v, 2, 64);
        v += __shfl_xor(v, 4, 64);
        v += __shfl_xor(v, 8, 64);
        if (l15 == 0) {
          int rl = wv * 32 + mt * 16 + quad * 4 + r2;
          atomicAdd(&sums[(size_t)mat * B + mbase + rl], v);
        }
      }
  }
}

extern "C" void kernel_launch(void* const* d_in, const int* in_sizes, int n_in,
                              void* d_out, int out_size, void* d_ws, size_t ws_size,
                              hipStream_t stream) {
  const int* ids = (const int*)d_in[0];
  const float* Eo = (const float*)d_in[1];
  const float* Ed = (const float*)d_in[2];
  const float* go = (const float*)d_in[3];
  const float* bo = (const float*)d_in[4];
  const float* gd = (const float*)d_in[5];
  const float* bd = (const float*)d_in[6];
  const int B = in_sizes[0];          // 512
  const int N = in_sizes[1] / DDIM;   // 100000
  float* out = (float*)d_out;

  char* ws = (char*)d_ws;
  size_t plane = (size_t)N * DDIM * sizeof(_Float16);  // 12.8 MB
  _Float16* Co_hi = (_Float16*)(ws + 0 * plane);
  _Float16* Co_lo = (_Float16*)(ws + 1 * plane);
  _Float16* Cd_hi = (_Float16*)(ws + 2 * plane);
  _Float16* Cd_lo = (_Float16*)(ws + 3 * plane);
  float* sums = (float*)(ws + 4 * plane);  // 2*B floats

  hipMemsetAsync(sums, 0, (size_t)2 * B * sizeof(float), stream);

  ln_kernel<<<(N + 3) / 4, 256, 0, stream>>>(Eo, Ed, go, bo, gd, bd,
                                             Co_hi, Co_lo, Cd_hi, Cd_lo, N);

  int nc_total = (N + CK - 1) / CK;  // 1563
  // 96 x-blocks * 4 * 2 = 768 blocks = 3 blocks/CU x 256 CU: ONE scheduling
  // round, Q-staging amortized over ~16 chunks/block. Blocks sharing a
  // chunk stream are 96 apart (96 % 8 == 0 -> same XCD -> L2 hits).
  dim3 sgrid(96, B / RB, 2);
  score_kernel<0><<<sgrid, 256, 0, stream>>>(Co_hi, Co_lo, Cd_hi, Cd_lo, ids,
                                             sums, out, N, B, nc_total);
  score_kernel<1><<<sgrid, 256, 0, stream>>>(Co_hi, Co_lo, Cd_hi, Cd_lo, ids,
                                             sums, out, N, B, nc_total);
}

// Round 6
// 528.764 us; speedup vs baseline: 1.3764x; 1.1049x over previous
//
#include <hip/hip_runtime.h>

typedef _Float16 half8 __attribute__((ext_vector_type(8)));
typedef float floatx4 __attribute__((ext_vector_type(4)));

#define DDIM 64
#define LN_EPS 1e-5f
#define SHIFT 20.0f

#define RB 128        // query rows per block
#define CK 64         // C rows (score cols) per chunk
#define STR 72        // LDS row stride in f16 elems (144 B)
#define ROWB (STR * 2)   // 144 bytes per LDS row
#define PLB (CK * ROWB)  // 9216 bytes per plane buffer
#define PSTR 68       // Pbuf row stride in floats (272 B, 16B-aligned)

__device__ inline float wave_sum(float v) {
#pragma unroll
  for (int m = 1; m < 64; m <<= 1) v += __shfl_xor(v, m, 64);
  return v;
}

// LayerNorm both tables, emit f16 hi/lo split planes. One wave per row.
__global__ __launch_bounds__(256) void ln_kernel(
    const float* __restrict__ Eo, const float* __restrict__ Ed,
    const float* __restrict__ go, const float* __restrict__ bo,
    const float* __restrict__ gd, const float* __restrict__ bd,
    _Float16* __restrict__ Co_hi, _Float16* __restrict__ Co_lo,
    _Float16* __restrict__ Cd_hi, _Float16* __restrict__ Cd_lo, int N) {
  int row = blockIdx.x * 4 + (threadIdx.x >> 6);
  if (row >= N) return;
  int lane = threadIdx.x & 63;
  size_t idx = (size_t)row * DDIM + lane;
  {
    float x = Eo[idx];
    float m = wave_sum(x) * (1.0f / DDIM);
    float d = x - m;
    float var = wave_sum(d * d) * (1.0f / DDIM);
    float y = d * rsqrtf(var + LN_EPS) * go[lane] + bo[lane];
    _Float16 hi = (_Float16)y;
    Co_hi[idx] = hi;
    Co_lo[idx] = (_Float16)(y - (float)hi);
  }
  {
    float x = Ed[idx];
    float m = wave_sum(x) * (1.0f / DDIM);
    float d = x - m;
    float var = wave_sum(d * d) * (1.0f / DDIM);
    float y = d * rsqrtf(var + LN_EPS) * gd[lane] + bd[lane];
    _Float16 hi = (_Float16)y;
    Cd_hi[idx] = hi;
    Cd_lo[idx] = (_Float16)(y - (float)hi);
  }
}

// Two-pass softmax. PASS 0: accumulate sum of exp(score - SHIFT) per row
// (atomics) — compute-only, cheap. PASS 1: write exp(score-SHIFT)*inv_sum.
// PASS 1 output path: p values go through an LDS transpose tile (Pbuf) and
// are flushed as 256 B contiguous per-row segments (row stride 400000 B is
// 128B-aligned) -> full-line HBM writes, no L2 read-modify-write. The flush
// of chunk k overlaps the stage of chunk k+1 (disjoint LDS regions).
// Scores via split-f16 MFMA: s = qh*ch + qh*cl + ql*ch (ql*cl dropped).
template <int PASS>
__global__ __launch_bounds__(256, 3) void score_kernel(
    const _Float16* __restrict__ Co_hi, const _Float16* __restrict__ Co_lo,
    const _Float16* __restrict__ Cd_hi, const _Float16* __restrict__ Cd_lo,
    const int* __restrict__ ids, float* __restrict__ sums,
    float* __restrict__ out, int N, int B, int nc_total) {
  // Sbuf: [2 planes][64 rows][144 B] = 18432 B; reused for Q staging.
  __shared__ __attribute__((aligned(16))) char Sbuf[2 * PLB];
  // Pbuf (PASS 1 only): 128 rows x 68 floats = 34816 B.
  // Total PASS1 LDS = 18432 + 34816 + 512 = 53760 B -> 3 blocks/CU.
  __shared__ __attribute__((aligned(16))) float Pbuf[PASS == 1 ? RB * PSTR : 1];
  __shared__ float inv_lds[RB];

  const int t = threadIdx.x;
  const int mat = blockIdx.z;
  const int mbase = blockIdx.y * RB;
  const _Float16* Qsrc_h = (mat == 0) ? Co_hi : Cd_hi;
  const _Float16* Qsrc_l = (mat == 0) ? Co_lo : Cd_lo;
  const _Float16* Csrc_h = (mat == 0) ? Cd_hi : Co_hi;
  const _Float16* Csrc_l = (mat == 0) ? Cd_lo : Co_lo;

  const int lane = t & 63;
  const int wv = t >> 6;
  const int l15 = lane & 15;
  const int quad = lane >> 4;

  if (PASS == 1 && t < RB)
    inv_lds[t] = 1.0f / sums[(size_t)mat * B + mbase + t];

  // ---- Stage Q-hi into Sbuf as [128 rows][144 B], read A-hi frags.
#pragma unroll
  for (int j = 0; j < 4; ++j) {
    int f = (j * 256 + t) * 16;  // byte offset in [128][128B] plane image
    int r = f >> 7;
    int off = f & 127;
    int id = ids[mbase + r];
    *(uint4*)(Sbuf + r * ROWB + off) =
        *(const uint4*)((const char*)Qsrc_h + (size_t)id * 128 + off);
  }
  __syncthreads();
  half8 Ah[2][2], Al[2][2];
#pragma unroll
  for (int mt = 0; mt < 2; ++mt) {
    int r = wv * 32 + mt * 16 + l15;
    const char* q = Sbuf + r * ROWB + quad * 16;
    Ah[mt][0] = *(const half8*)q;
    Ah[mt][1] = *(const half8*)(q + 64);
  }
  float invr[2][4];
  if (PASS == 1) {
#pragma unroll
    for (int mt = 0; mt < 2; ++mt)
#pragma unroll
      for (int r2 = 0; r2 < 4; ++r2)
        invr[mt][r2] = inv_lds[wv * 32 + mt * 16 + quad * 4 + r2];
  }
  __syncthreads();
  // ---- Stage Q-lo (same layout), read A-lo frags.
#pragma unroll
  for (int j = 0; j < 4; ++j) {
    int f = (j * 256 + t) * 16;
    int r = f >> 7;
    int off = f & 127;
    int id = ids[mbase + r];
    *(uint4*)(Sbuf + r * ROWB + off) =
        *(const uint4*)((const char*)Qsrc_l + (size_t)id * 128 + off);
  }
  __syncthreads();
#pragma unroll
  for (int mt = 0; mt < 2; ++mt) {
    int r = wv * 32 + mt * 16 + l15;
    const char* q = Sbuf + r * ROWB + quad * 16;
    Al[mt][0] = *(const half8*)q;
    Al[mt][1] = *(const half8*)(q + 64);
  }
  __syncthreads();  // Q reads done; Sbuf free for C chunks

  float sumacc[2][4];
#pragma unroll
  for (int mt = 0; mt < 2; ++mt)
#pragma unroll
    for (int r2 = 0; r2 < 4; ++r2) sumacc[mt][r2] = 0.0f;

  const int bx = blockIdx.x;
  const int gxd = gridDim.x;
  // strided chunk assignment: chunks bx, bx+gxd, bx+2*gxd, ...
  int nck = (bx < nc_total) ? ((nc_total - 1 - bx) / gxd + 1) : 0;
  float* orow = out + (size_t)mat * B * N + (size_t)mbase * N;

  for (int k = 0; k < nck; ++k) {
    int nbase = (bx + k * gxd) * CK;
    // stage C chunk (both planes): 64 rows x 128 B each, [r][144B] layout
#pragma unroll
    for (int p = 0; p < 2; ++p) {
      const char* src = (p == 0) ? (const char*)Csrc_h : (const char*)Csrc_l;
#pragma unroll
      for (int j = 0; j < 2; ++j) {
        int f = (j * 256 + t) * 16;
        int r = f >> 7;
        int off = f & 127;
        int gr = nbase + r;
        if (gr > N - 1) gr = N - 1;  // clamp; masked at use
        *(uint4*)(Sbuf + p * PLB + r * ROWB + off) =
            *(const uint4*)(src + (size_t)gr * 128 + off);
      }
    }
    __syncthreads();  // chunk staged (and, for PASS1, prev flush done)

#pragma unroll
    for (int nt = 0; nt < 4; ++nt) {
      int cr = nt * 16 + l15;
      const char* bh = Sbuf + cr * ROWB + quad * 16;
      const char* bl = bh + PLB;
      half8 Bh0 = *(const half8*)bh;
      half8 Bh1 = *(const half8*)(bh + 64);
      half8 Bl0 = *(const half8*)bl;
      half8 Bl1 = *(const half8*)(bl + 64);
      int col = nbase + nt * 16 + l15;
      bool valid = col < N;
#pragma unroll
      for (int mt = 0; mt < 2; ++mt) {
        floatx4 acc = {0.0f, 0.0f, 0.0f, 0.0f};
        acc = __builtin_amdgcn_mfma_f32_16x16x32_f16(Ah[mt][0], Bh0, acc, 0, 0, 0);
        acc = __builtin_amdgcn_mfma_f32_16x16x32_f16(Ah[mt][1], Bh1, acc, 0, 0, 0);
        acc = __builtin_amdgcn_mfma_f32_16x16x32_f16(Ah[mt][0], Bl0, acc, 0, 0, 0);
        acc = __builtin_amdgcn_mfma_f32_16x16x32_f16(Ah[mt][1], Bl1, acc, 0, 0, 0);
        acc = __builtin_amdgcn_mfma_f32_16x16x32_f16(Al[mt][0], Bh0, acc, 0, 0, 0);
        acc = __builtin_amdgcn_mfma_f32_16x16x32_f16(Al[mt][1], Bh1, acc, 0, 0, 0);
#pragma unroll
        for (int r2 = 0; r2 < 4; ++r2) {
          float p = __expf(acc[r2] - SHIFT);
          if (PASS == 0) {
            sumacc[mt][r2] += valid ? p : 0.0f;
          } else {
            int rl = wv * 32 + mt * 16 + quad * 4 + r2;
            Pbuf[rl * PSTR + nt * 16 + l15] = p * invr[mt][r2];
          }
        }
      }
    }
    if (PASS == 0) {
      __syncthreads();  // Sbuf reads done before next stage
    } else {
      __syncthreads();  // Pbuf complete + Sbuf reads done
      // Flush Pbuf -> out: 128 rows x 64 cols; 16 threads/row, floatx4 each
      // -> 256 B contiguous per row, all segments 128B-aligned.
#pragma unroll
      for (int i = 0; i < 8; ++i) {
        int fl = i * 256 + t;   // 0..2047
        int row = fl >> 4;      // 0..127
        int c4 = fl & 15;       // 0..15 (float4 index within row)
        int gcol = nbase + c4 * 4;
        if (gcol < N) {         // N%4==0 -> uniform validity per float4
          floatx4 v = *(const floatx4*)&Pbuf[row * PSTR + c4 * 4];
          __builtin_nontemporal_store(
              v, (floatx4*)(orow + (size_t)row * N + gcol));
        }
      }
      // no extra barrier: next iteration's post-stage barrier orders
      // this flush (Pbuf reads) before the next compute's Pbuf writes.
    }
  }

  if (PASS == 0) {
    // per-row partial sums -> atomics (reduce across 16 lanes of row group)
#pragma unroll
    for (int mt = 0; mt < 2; ++mt)
#pragma unroll
      for (int r2 = 0; r2 < 4; ++r2) {
        float v = sumacc[mt][r2];
        v += __shfl_xor(v, 1, 64);
        v += __shfl_xor(v, 2, 64);
        v += __shfl_xor(v, 4, 64);
        v += __shfl_xor(v, 8, 64);
        if (l15 == 0) {
          int rl = wv * 32 + mt * 16 + quad * 4 + r2;
          atomicAdd(&sums[(size_t)mat * B + mbase + rl], v);
        }
      }
  }
}

extern "C" void kernel_launch(void* const* d_in, const int* in_sizes, int n_in,
                              void* d_out, int out_size, void* d_ws, size_t ws_size,
                              hipStream_t stream) {
  const int* ids = (const int*)d_in[0];
  const float* Eo = (const float*)d_in[1];
  const float* Ed = (const float*)d_in[2];
  const float* go = (const float*)d_in[3];
  const float* bo = (const float*)d_in[4];
  const float* gd = (const float*)d_in[5];
  const float* bd = (const float*)d_in[6];
  const int B = in_sizes[0];          // 512
  const int N = in_sizes[1] / DDIM;   // 100000
  float* out = (float*)d_out;

  char* ws = (char*)d_ws;
  size_t plane = (size_t)N * DDIM * sizeof(_Float16);  // 12.8 MB
  _Float16* Co_hi = (_Float16*)(ws + 0 * plane);
  _Float16* Co_lo = (_Float16*)(ws + 1 * plane);
  _Float16* Cd_hi = (_Float16*)(ws + 2 * plane);
  _Float16* Cd_lo = (_Float16*)(ws + 3 * plane);
  float* sums = (float*)(ws + 4 * plane);  // 2*B floats

  (void)hipMemsetAsync(sums, 0, (size_t)2 * B * sizeof(float), stream);

  ln_kernel<<<(N + 3) / 4, 256, 0, stream>>>(Eo, Ed, go, bo, gd, bd,
                                             Co_hi, Co_lo, Cd_hi, Cd_lo, N);

  int nc_total = (N + CK - 1) / CK;  // 1563
  // 96 x-blocks * 4 * 2 = 768 blocks = 3 blocks/CU x 256 CU: one scheduling
  // round. Blocks sharing a chunk stream are 96 apart (96 % 8 == 0 -> same
  // XCD -> L2 reuse of C chunks).
  dim3 sgrid(96, B / RB, 2);
  score_kernel<0><<<sgrid, 256, 0, stream>>>(Co_hi, Co_lo, Cd_hi, Cd_lo, ids,
                                             sums, out, N, B, nc_total);
  score_kernel<1><<<sgrid, 256, 0, stream>>>(Co_hi, Co_lo, Cd_hi, Cd_lo, ids,
                                             sums, out, N, B, nc_total);
}